// Round 1
// baseline (262.195 us; speedup 1.0000x reference)
//
#include <hip/hip_runtime.h>

#define H 8
#define DH 64
#define NQ 1024
#define NK 2048
#define DIN 512

typedef __bf16 bf16;
typedef __bf16 bf16x8 __attribute__((ext_vector_type(8)));
typedef __bf16 bf16x4 __attribute__((ext_vector_type(4)));
typedef float floatx4 __attribute__((ext_vector_type(4)));

__device__ inline void gload16(const void* g, void* l) {
  __builtin_amdgcn_global_load_lds(
      (const __attribute__((address_space(1))) void*)g,
      (__attribute__((address_space(3))) void*)l, 16, 0, 0);
}

// ---------------- fp32 -> bf16 convert ----------------
__global__ void cvt_kernel(const float* __restrict__ src, bf16* __restrict__ dst, int n) {
  int i = (blockIdx.x * 256 + threadIdx.x) * 4;
  if (i >= n) return;
  const float4 f = *(const float4*)(src + i);
  bf16x4 o = { (bf16)f.x, (bf16)f.y, (bf16)f.z, (bf16)f.w };
  *(bf16x4*)(dst + i) = o;
}

// ---------------- GEMM: C = A @ W^T  (A: MxK row-major, W: NxK row-major) ----------
// MODE 0: bf16 out as [b,h,tok,d]   (Q, K)   -- scale applied
// MODE 1: bf16 out as [b,h,d,tok]   (V^T)
// MODE 2: fp32 out [m,n] + bias bo[n]  (final projection)
template<int MODE>
__global__ __launch_bounds__(256) void gemm_bt(
    const bf16* __restrict__ A, const bf16* __restrict__ W,
    bf16* __restrict__ outb, float* __restrict__ outf,
    const float* __restrict__ bo, int logT, float scale) {
  __shared__ bf16 Al[128 * 32];
  __shared__ bf16 Bl[128 * 32];
  const int t = threadIdx.x;
  const int lane = t & 63, w = t >> 6;
  const int ln = lane & 15, quad = lane >> 4;
  const int wm = (w >> 1) * 64, wn = (w & 1) * 64;
  const int rowBase = blockIdx.y * 128;
  const int colBase = blockIdx.x * 128;

  floatx4 acc[4][4] = {};
  const int c0 = t, c1 = t + 256;
  const int r0 = c0 >> 2, o0 = (c0 & 3) * 8;
  const int r1 = c1 >> 2, o1 = (c1 & 3) * 8;
  const bf16* Ab = A + (size_t)rowBase * DIN;
  const bf16* Wb = W + (size_t)colBase * DIN;

  for (int k0 = 0; k0 < DIN; k0 += 32) {
    gload16(Ab + (size_t)r0 * DIN + k0 + o0, &Al[c0 * 8]);
    gload16(Ab + (size_t)r1 * DIN + k0 + o1, &Al[c1 * 8]);
    gload16(Wb + (size_t)r0 * DIN + k0 + o0, &Bl[c0 * 8]);
    gload16(Wb + (size_t)r1 * DIN + k0 + o1, &Bl[c1 * 8]);
    __syncthreads();
    bf16x8 af[4], bfr[4];
#pragma unroll
    for (int i = 0; i < 4; i++)
      af[i] = *(const bf16x8*)&Al[(wm + i * 16 + ln) * 32 + quad * 8];
#pragma unroll
    for (int j = 0; j < 4; j++)
      bfr[j] = *(const bf16x8*)&Bl[(wn + j * 16 + ln) * 32 + quad * 8];
#pragma unroll
    for (int i = 0; i < 4; i++)
#pragma unroll
      for (int j = 0; j < 4; j++)
        acc[i][j] = __builtin_amdgcn_mfma_f32_16x16x32_bf16(af[i], bfr[j], acc[i][j], 0, 0, 0);
    __syncthreads();
  }

  const int T = 1 << logT;
#pragma unroll
  for (int i = 0; i < 4; i++) {
#pragma unroll
    for (int j = 0; j < 4; j++) {
#pragma unroll
      for (int r = 0; r < 4; r++) {
        const int m = rowBase + wm + i * 16 + quad * 4 + r;
        const int n = colBase + wn + j * 16 + ln;
        float v = acc[i][j][r] * scale;
        if (MODE == 0) {
          const int b = m >> logT, tok = m & (T - 1);
          const int hh = n >> 6, d = n & 63;
          outb[((((size_t)(b * H + hh)) << logT) + tok) * DH + d] = (bf16)v;
        } else if (MODE == 1) {
          const int b = m >> logT, tok = m & (T - 1);
          const int hh = n >> 6, d = n & 63;
          outb[(((size_t)(b * H + hh) * DH + d) << logT) + tok] = (bf16)v;
        } else {
          outf[(size_t)m * DIN + n] = v + bo[n];
        }
      }
    }
  }
}

// ---------------- flash attention ----------------
// grid: (NQ/64, H, B), block 256 (4 waves; wave w owns q-rows q0+w*16 .. +15)
__global__ __launch_bounds__(256) void attn_fwd(
    const bf16* __restrict__ q, const bf16* __restrict__ k,
    const bf16* __restrict__ vt, const float* __restrict__ bias,
    bf16* __restrict__ aout) {
  __shared__ bf16 Kl[64 * 64];
  __shared__ bf16 Vl[64 * 64];
  __shared__ bf16 Pl[4][16 * 64];
  const int t = threadIdx.x;
  const int lane = t & 63, w = t >> 6;
  const int ln = lane & 15, quad = lane >> 4;
  const int hh = blockIdx.y, b = blockIdx.z;
  const int q0 = blockIdx.x * 64;
  const size_t bh = (size_t)b * H + hh;
  const bf16* qp = q + bh * NQ * DH;
  const bf16* kp = k + bh * NK * DH;
  const bf16* vp = vt + bh * DH * NK;

  bf16x8 qf[2];
#pragma unroll
  for (int kc = 0; kc < 2; kc++)
    qf[kc] = *(const bf16x8*)(qp + (size_t)(q0 + w * 16 + ln) * DH + kc * 32 + quad * 8);

  float m_i[4], l_i[4];
  floatx4 o[4] = {};
#pragma unroll
  for (int r = 0; r < 4; r++) { m_i[r] = -__builtin_inff(); l_i[r] = 0.f; }

  const float* bp = bias + ((size_t)b * NQ + q0 + w * 16 + quad * 4) * NK;
  constexpr float L2E = 1.44269504f;

  for (int nk0 = 0; nk0 < NK; nk0 += 64) {
#pragma unroll
    for (int s = 0; s < 2; s++) {
      const int c = t + s * 256;
      const int row = c >> 3, off = (c & 7) * 8;
      gload16(kp + (size_t)(nk0 + row) * DH + off, &Kl[c * 8]);
      gload16(vp + (size_t)row * NK + nk0 + off, &Vl[c * 8]);
    }
    __syncthreads();

    floatx4 s4[4] = {};
#pragma unroll
    for (int j = 0; j < 4; j++) {
#pragma unroll
      for (int kc = 0; kc < 2; kc++) {
        bf16x8 kf = *(const bf16x8*)&Kl[(j * 16 + ln) * 64 + kc * 32 + quad * 8];
        s4[j] = __builtin_amdgcn_mfma_f32_16x16x32_bf16(qf[kc], kf, s4[j], 0, 0, 0);
      }
    }
    // add fp32 bias (scale already folded into q)
#pragma unroll
    for (int j = 0; j < 4; j++)
#pragma unroll
      for (int r = 0; r < 4; r++)
        s4[j][r] += bp[(size_t)r * NK + nk0 + j * 16 + ln];

    // online softmax over this 64-col tile (rows are wave-private)
    float mloc[4], lloc[4], al[4];
#pragma unroll
    for (int r = 0; r < 4; r++)
      mloc[r] = fmaxf(fmaxf(s4[0][r], s4[1][r]), fmaxf(s4[2][r], s4[3][r]));
#pragma unroll
    for (int d = 1; d < 16; d <<= 1)
#pragma unroll
      for (int r = 0; r < 4; r++)
        mloc[r] = fmaxf(mloc[r], __shfl_xor(mloc[r], d, 64));
#pragma unroll
    for (int r = 0; r < 4; r++) {
      const float mn = fmaxf(m_i[r], mloc[r]);
      al[r] = exp2f((m_i[r] - mn) * L2E);
      m_i[r] = mn;
      lloc[r] = 0.f;
    }
#pragma unroll
    for (int j = 0; j < 4; j++)
#pragma unroll
      for (int r = 0; r < 4; r++) {
        const float p = exp2f((s4[j][r] - m_i[r]) * L2E);
        s4[j][r] = p;
        lloc[r] += p;
      }
#pragma unroll
    for (int d = 1; d < 16; d <<= 1)
#pragma unroll
      for (int r = 0; r < 4; r++)
        lloc[r] += __shfl_xor(lloc[r], d, 64);
#pragma unroll
    for (int r = 0; r < 4; r++)
      l_i[r] = l_i[r] * al[r] + lloc[r];
#pragma unroll
    for (int jn = 0; jn < 4; jn++)
#pragma unroll
      for (int r = 0; r < 4; r++)
        o[jn][r] *= al[r];

    // P (C-layout) -> per-wave LDS -> A-layout fragments
    bf16* pl = &Pl[w][0];
#pragma unroll
    for (int j = 0; j < 4; j++)
#pragma unroll
      for (int r = 0; r < 4; r++)
        pl[(quad * 4 + r) * 64 + j * 16 + ln] = (bf16)s4[j][r];
    asm volatile("s_waitcnt lgkmcnt(0)" ::: "memory");
    bf16x8 pf[2];
#pragma unroll
    for (int kc = 0; kc < 2; kc++)
      pf[kc] = *(const bf16x8*)&pl[ln * 64 + kc * 32 + quad * 8];
#pragma unroll
    for (int jn = 0; jn < 4; jn++) {
#pragma unroll
      for (int kc = 0; kc < 2; kc++) {
        bf16x8 vf = *(const bf16x8*)&Vl[(jn * 16 + ln) * 64 + kc * 32 + quad * 8];
        o[jn] = __builtin_amdgcn_mfma_f32_16x16x32_bf16(pf[kc], vf, o[jn], 0, 0, 0);
      }
    }
    __syncthreads();
  }

  float inv[4];
#pragma unroll
  for (int r = 0; r < 4; r++) inv[r] = 1.0f / l_i[r];
#pragma unroll
  for (int jn = 0; jn < 4; jn++)
#pragma unroll
    for (int r = 0; r < 4; r++) {
      const size_t row = (size_t)b * NQ + q0 + w * 16 + quad * 4 + r;
      aout[row * DIN + hh * 64 + jn * 16 + ln] = (bf16)(o[jn][r] * inv[r]);
    }
}

extern "C" void kernel_launch(void* const* d_in, const int* in_sizes, int n_in,
                              void* d_out, int out_size, void* d_ws, size_t ws_size,
                              hipStream_t stream) {
  const float* x    = (const float*)d_in[0];
  const float* ctx  = (const float*)d_in[1];
  const float* bias = (const float*)d_in[2];
  const float* Wq   = (const float*)d_in[3];
  const float* Wk   = (const float*)d_in[4];
  const float* Wv   = (const float*)d_in[5];
  const float* Wo   = (const float*)d_in[6];
  const float* bo   = (const float*)d_in[7];
  float* out = (float*)d_out;

  char* p = (char*)d_ws;
  bf16* xb  = (bf16*)p; p += (size_t)4096 * 512 * 2;
  bf16* cb  = (bf16*)p; p += (size_t)8192 * 512 * 2;
  bf16* wqb = (bf16*)p; p += (size_t)512 * 512 * 2;
  bf16* wkb = (bf16*)p; p += (size_t)512 * 512 * 2;
  bf16* wvb = (bf16*)p; p += (size_t)512 * 512 * 2;
  bf16* wob = (bf16*)p; p += (size_t)512 * 512 * 2;
  bf16* qb  = (bf16*)p; p += (size_t)4096 * 512 * 2;
  bf16* kb  = (bf16*)p; p += (size_t)8192 * 512 * 2;
  bf16* vtb = (bf16*)p; p += (size_t)8192 * 512 * 2;
  bf16* ab  = (bf16*)p; p += (size_t)4096 * 512 * 2;

  cvt_kernel<<<(4096 * 512) / 1024, 256, 0, stream>>>(x, xb, 4096 * 512);
  cvt_kernel<<<(8192 * 512) / 1024, 256, 0, stream>>>(ctx, cb, 8192 * 512);
  cvt_kernel<<<(512 * 512) / 1024, 256, 0, stream>>>(Wq, wqb, 512 * 512);
  cvt_kernel<<<(512 * 512) / 1024, 256, 0, stream>>>(Wk, wkb, 512 * 512);
  cvt_kernel<<<(512 * 512) / 1024, 256, 0, stream>>>(Wv, wvb, 512 * 512);
  cvt_kernel<<<(512 * 512) / 1024, 256, 0, stream>>>(Wo, wob, 512 * 512);

  // Q = x@Wq^T (scale 0.125 folded in), K = ctx@Wk^T, V^T = (ctx@Wv^T)^T
  gemm_bt<0><<<dim3(4, 32), 256, 0, stream>>>(xb, wqb, qb, nullptr, nullptr, 10, 0.125f);
  gemm_bt<0><<<dim3(4, 64), 256, 0, stream>>>(cb, wkb, kb, nullptr, nullptr, 11, 1.0f);
  gemm_bt<1><<<dim3(4, 64), 256, 0, stream>>>(cb, wvb, vtb, nullptr, nullptr, 11, 1.0f);

  attn_fwd<<<dim3(NQ / 64, H, 4), 256, 0, stream>>>(qb, kb, vtb, bias, ab);

  gemm_bt<2><<<dim3(4, 32), 256, 0, stream>>>(ab, wob, nullptr, out, bo, 10, 1.0f);
}